// Round 2
// baseline (392.636 us; speedup 1.0000x reference)
//
#include <hip/hip_runtime.h>

#define NWIN 640
#define ZHW  144
#define DIM  192
#define HEADS 6
#define DH   32
#define TW   64
#define RSCALE 0.17677669529663689f

typedef float f32x4 __attribute__((ext_vector_type(4)));
typedef __bf16 bf16x8 __attribute__((ext_vector_type(8)));

__device__ __forceinline__ unsigned short f2b(float f) {
  unsigned u = __float_as_uint(f);
  u += 0x7fffu + ((u >> 16) & 1u);
  return (unsigned short)(u >> 16);
}
__device__ __forceinline__ float b2f(unsigned v) { return __uint_as_float(v << 16); }

// A/B fragment for mfma_f32_16x16x32_bf16 from a row-major array:
// lane reads elements k0..k0+3 and k0+16..k0+19 of its row (k0 = 4*(lane>>4)).
__device__ __forceinline__ bf16x8 ld_frag(const unsigned short* p) {
  uint2 lo = *(const uint2*)(p);
  uint2 hi = *(const uint2*)(p + 16);
  uint4 u; u.x = lo.x; u.y = lo.y; u.z = hi.x; u.w = hi.y;
  return __builtin_bit_cast(bf16x8, u);
}
#define MFMA16(a, b, c) __builtin_amdgcn_mfma_f32_16x16x32_bf16((a), (b), (c), 0, 0, 0)

// ======================= QKV projection per window =======================
// x(144x192 f32) @ w1(192x576) + b1 -> q,k row-major [m][144][32] bf16,
// v transposed [m][32][144] bf16, with m = h*640 + win.
#define XQ_LD 196
#define WQ_LD 196
__global__ __launch_bounds__(576) void qkv_kernel(
    const float* __restrict__ x, const float* __restrict__ b1,
    const unsigned short* __restrict__ w1t,
    unsigned short* __restrict__ qb, unsigned short* __restrict__ kb,
    unsigned short* __restrict__ vb)
{
  __shared__ __align__(16) unsigned char smem[131712];
  unsigned short* xs = (unsigned short*)smem;            // [144][196]
  unsigned short* wb = (unsigned short*)(smem + 56448);  // [192][196]
  const int tid = threadIdx.x, wv = tid >> 6, lane = tid & 63;
  const int l15 = lane & 15, g = lane >> 4;
  const int win = blockIdx.x;

  {
    const float4* src = (const float4*)(x + (size_t)win * ZHW * DIM);
    #pragma unroll 1
    for (int i = tid; i < ZHW * DIM / 4; i += 576) {
      float4 v = src[i];
      int e = i * 4, r = e / DIM, c = e % DIM;
      uint2 pk;
      pk.x = (unsigned)f2b(v.x) | ((unsigned)f2b(v.y) << 16);
      pk.y = (unsigned)f2b(v.z) | ((unsigned)f2b(v.w) << 16);
      *(uint2*)(xs + r * XQ_LD + c) = pk;
    }
  }
  #pragma unroll 1
  for (int c = 0; c < 3; ++c) {
    __syncthreads();  // protect wb from previous chunk's readers (1st: x publish)
    {
      const uint2* wsrc = (const uint2*)(w1t + (size_t)c * DIM * DIM);
      #pragma unroll 1
      for (int i = tid; i < DIM * DIM / 4; i += 576) {
        int e = i * 4, r = e / DIM, cc = e % DIM;
        *(uint2*)(wb + r * WQ_LD + cc) = wsrc[i];
      }
    }
    __syncthreads();
    bf16x8 a[6];
    const unsigned short* arow = xs + (16 * wv + l15) * XQ_LD + 4 * g;
    #pragma unroll
    for (int kk = 0; kk < 6; ++kk) a[kk] = ld_frag(arow + kk * 32);
    unsigned short* qk = (c == 0) ? qb : kb;
    #pragma unroll 1
    for (int nt = 0; nt < 12; ++nt) {
      float bv = b1[c * DIM + nt * 16 + l15];
      f32x4 acc; acc[0] = bv; acc[1] = bv; acc[2] = bv; acc[3] = bv;
      const unsigned short* brow = wb + (nt * 16 + l15) * WQ_LD + 4 * g;
      #pragma unroll
      for (int kk = 0; kk < 6; ++kk) acc = MFMA16(a[kk], ld_frag(brow + kk * 32), acc);
      const int h = nt >> 1, d = ((nt & 1) << 4) + l15;
      const size_t base = (size_t)(h * NWIN + win) * (ZHW * DH);
      if (c < 2) {  // row-major [144][32], row = 16wv+4g+j, col = d
        unsigned short* dst = qk + base + (size_t)(16 * wv + 4 * g) * DH + d;
        dst[0]      = f2b(acc[0]);
        dst[DH]     = f2b(acc[1]);
        dst[2 * DH] = f2b(acc[2]);
        dst[3 * DH] = f2b(acc[3]);
      } else {      // transposed [32][144]: 4 consecutive tokens pack to uint2
        uint2 pk;
        pk.x = (unsigned)f2b(acc[0]) | ((unsigned)f2b(acc[1]) << 16);
        pk.y = (unsigned)f2b(acc[2]) | ((unsigned)f2b(acc[3]) << 16);
        *(uint2*)(vb + base + (size_t)d * ZHW + 16 * wv + 4 * g) = pk;
      }
    }
  }
}

// ================= attention + fused out-projection per (win,head) ==========
// Block m = h*640+win owns out rows [24m, 24m+24): computes S=KQ^T, softmax,
// O^T=V^T P^T into LDS (scrambled layout), then O(24x192) @ w2 + b2 -> out.
#define KS_LD 36
#define VT_LD 164
#define OL_LD 200
#define A2_SMEM 33664
__global__ __launch_bounds__(256) void attn2_kernel(
    const unsigned short* __restrict__ qb, const unsigned short* __restrict__ kb,
    const unsigned short* __restrict__ vb, const unsigned short* __restrict__ biasm,
    const unsigned char* __restrict__ msk, const unsigned short* __restrict__ w2t,
    const float* __restrict__ b2, float* __restrict__ out)
{
  __shared__ __align__(16) unsigned char smem[A2_SMEM];
  unsigned short* ks = (unsigned short*)(smem);          // [144][36]
  unsigned short* vt = (unsigned short*)(smem + 10368);  // [32][164] (pad cols 0)
  unsigned short* ol = (unsigned short*)(smem + 20864);  // [32][200] (rows 24..31 zero)
  const int tid = threadIdx.x, wv = tid >> 6, lane = tid & 63;
  const int l15 = lane & 15, g = lane >> 4;
  const int m = blockIdx.x, h = m / NWIN, win = m - h * NWIN, wtype = win & (TW - 1);
  const size_t base = (size_t)m * (ZHW * DH);

  {
    const uint2* src = (const uint2*)(kb + base);
    #pragma unroll 1
    for (int i = tid; i < ZHW * DH / 4; i += 256) {
      int e = i * 4, r = e / DH, c = e - r * DH;
      *(uint2*)(ks + r * KS_LD + c) = src[i];
    }
  }
  {
    const uint2* src = (const uint2*)(vb + base);
    #pragma unroll 1
    for (int i = tid; i < DH * ZHW / 4; i += 256) {
      int e = i * 4, r = e / ZHW, c = e - r * ZHW;
      *(uint2*)(vt + r * VT_LD + c) = src[i];
    }
  }
  #pragma unroll 1
  for (int i = tid; i < DH * (VT_LD - ZHW); i += 256) {
    int r = i / (VT_LD - ZHW), c = ZHW + i - (i / (VT_LD - ZHW)) * (VT_LD - ZHW);
    vt[r * VT_LD + c] = 0;
  }
  #pragma unroll 1
  for (int i = tid; i < 8 * OL_LD; i += 256) {
    int r = 24 + i / OL_LD, c = i - (i / OL_LD) * OL_LD;
    ol[r * OL_LD + c] = 0;
  }
  __syncthreads();

  const unsigned short* qg = qb + base;
  const unsigned short* brow0 = biasm + (size_t)(wtype * HEADS + h) * (ZHW * ZHW);
  const unsigned char*  mrow0 = msk + (size_t)win * (ZHW * ZHW);

  #pragma unroll 1
  for (int s = wv; s < 9; s += 4) {   // q-strip [16s, 16s+16)
    const int q = 16 * s + l15;
    bf16x8 bq = ld_frag(qg + (size_t)q * DH + 4 * g);
    f32x4 st[9];
    #pragma unroll
    for (int kst = 0; kst < 9; ++kst) {
      bf16x8 ak = ld_frag(ks + (16 * kst + l15) * KS_LD + 4 * g);
      f32x4 z; z[0] = 0.f; z[1] = 0.f; z[2] = 0.f; z[3] = 0.f;
      st[kst] = MFMA16(ak, bq, z);   // St[kk=16kst+4g+j][q]
    }
    const unsigned short* brow = brow0 + q * ZHW;
    const unsigned char*  mrow = mrow0 + q * ZHW;
    float mx = -1e30f;
    #pragma unroll
    for (int kst = 0; kst < 9; ++kst) {
      int kk0 = kst * 16 + 4 * g;
      uint2 bb = *(const uint2*)(brow + kk0);
      unsigned mm = *(const unsigned*)(mrow + kk0);
      f32x4 sv = st[kst];
      sv[0] = sv[0] * RSCALE + b2f(bb.x & 0xffffu) + ((mm & 0xffu)       ? -100.f : 0.f);
      sv[1] = sv[1] * RSCALE + b2f(bb.x >> 16)     + ((mm & 0xff00u)     ? -100.f : 0.f);
      sv[2] = sv[2] * RSCALE + b2f(bb.y & 0xffffu) + ((mm & 0xff0000u)   ? -100.f : 0.f);
      sv[3] = sv[3] * RSCALE + b2f(bb.y >> 16)     + ((mm & 0xff000000u) ? -100.f : 0.f);
      st[kst] = sv;
      mx = fmaxf(mx, fmaxf(fmaxf(sv[0], sv[1]), fmaxf(sv[2], sv[3])));
    }
    mx = fmaxf(mx, __shfl_xor(mx, 16));
    mx = fmaxf(mx, __shfl_xor(mx, 32));
    float sum = 0.f;
    #pragma unroll
    for (int kst = 0; kst < 9; ++kst) {
      f32x4 sv = st[kst];
      sv[0] = __expf(sv[0] - mx); sv[1] = __expf(sv[1] - mx);
      sv[2] = __expf(sv[2] - mx); sv[3] = __expf(sv[3] - mx);
      st[kst] = sv;
      sum += sv[0] + sv[1] + sv[2] + sv[3];
    }
    sum += __shfl_xor(sum, 16);
    sum += __shfl_xor(sum, 32);
    float inv = 1.f / sum;
    bf16x8 pb[5];
    #pragma unroll
    for (int s5 = 0; s5 < 5; ++s5) {
      unsigned short e[8];
      #pragma unroll
      for (int j = 0; j < 4; ++j) e[j] = f2b(st[2 * s5][j] * inv);
      if (s5 < 4) {
        #pragma unroll
        for (int j = 0; j < 4; ++j) e[4 + j] = f2b(st[2 * s5 + 1][j] * inv);
      } else {
        e[4] = 0; e[5] = 0; e[6] = 0; e[7] = 0;
      }
      uint4 u;
      u.x = (unsigned)e[0] | ((unsigned)e[1] << 16);
      u.y = (unsigned)e[2] | ((unsigned)e[3] << 16);
      u.z = (unsigned)e[4] | ((unsigned)e[5] << 16);
      u.w = (unsigned)e[6] | ((unsigned)e[7] << 16);
      pb[s5] = __builtin_bit_cast(bf16x8, u);
    }
    // O^T tile -> ol at scrambled (row=q/6, col=(q%6)*32+d)
    const int r = q / 6, cb = (q - r * 6) * DH;
    unsigned short* orow = ol + r * OL_LD + cb + 4 * g;
    #pragma unroll
    for (int dt = 0; dt < 2; ++dt) {
      const unsigned short* vrow = vt + (dt * 16 + l15) * VT_LD + 4 * g;
      f32x4 ot; ot[0] = 0.f; ot[1] = 0.f; ot[2] = 0.f; ot[3] = 0.f;
      #pragma unroll
      for (int s5 = 0; s5 < 5; ++s5)
        ot = MFMA16(ld_frag(vrow + s5 * 32), pb[s5], ot);
      uint2 pk;
      pk.x = (unsigned)f2b(ot[0]) | ((unsigned)f2b(ot[1]) << 16);
      pk.y = (unsigned)f2b(ot[2]) | ((unsigned)f2b(ot[3]) << 16);
      *(uint2*)(orow + dt * 16) = pk;
    }
  }
  __syncthreads();
  // fused out-projection: ol(24x192, rows 24..31 zero) @ w2t + b2
  #pragma unroll 1
  for (int p = wv; p < 24; p += 4) {
    const int mt = p / 12, nt = p - mt * 12;
    float bv = b2[nt * 16 + l15];
    f32x4 acc; acc[0] = bv; acc[1] = bv; acc[2] = bv; acc[3] = bv;
    const unsigned short* arow = ol + (mt * 16 + l15) * OL_LD + 4 * g;
    const unsigned short* brow = w2t + (size_t)(nt * 16 + l15) * DIM + 4 * g;
    #pragma unroll
    for (int kk = 0; kk < 6; ++kk)
      acc = MFMA16(ld_frag(arow + kk * 32), ld_frag(brow + kk * 32), acc);
    #pragma unroll
    for (int j = 0; j < 4; ++j) {
      int r = mt * 16 + 4 * g + j;
      if (r < 24) out[(size_t)(24 * m + r) * DIM + nt * 16 + l15] = acc[j];
    }
  }
}

// ---- prep: transpose weights to bf16 n-major ----
__global__ void prep_w(const float* __restrict__ w1, const float* __restrict__ w2,
                       unsigned short* __restrict__ w1t, unsigned short* __restrict__ w2t)
{
  int i = blockIdx.x * 256 + threadIdx.x;
  if (i < 576 * 192) { int n = i / 192, k = i % 192; w1t[i] = f2b(w1[k * 576 + n]); }
  if (i < 192 * 192) { int n = i / 192, k = i % 192; w2t[i] = f2b(w2[k * 192 + n]); }
}

// ---- prep: bias[wtype*6+h][q*144+kk] bf16 via LDS transpose ----
__global__ void prep_bias(const float* __restrict__ table, const int* __restrict__ pidx,
                          unsigned short* __restrict__ biasm)
{
  __shared__ float ld[64 * 385];
  const int tid = threadIdx.x;
  const int p0 = blockIdx.x * 64;
  #pragma unroll 1
  for (int i = tid; i < 64 * 384; i += 256) {
    int pl = i / 384, wh = i % 384;
    ld[pl * 385 + wh] = table[(size_t)pidx[p0 + pl] * 384 + wh];
  }
  __syncthreads();
  #pragma unroll 1
  for (int i = tid; i < 384 * 64; i += 256) {
    int wh = i / 64, pl = i % 64;
    biasm[(size_t)wh * (ZHW * ZHW) + p0 + pl] = f2b(ld[pl * 385 + wh]);
  }
}

// ---- prep: mask f32 -> u8 (0 / 1 meaning -100) ----
__global__ void prep_mask(const float* __restrict__ mask, unsigned char* __restrict__ msk)
{
  int i = blockIdx.x * 256 + threadIdx.x;  // one float4 -> one u32
  float4 v = ((const float4*)mask)[i];
  unsigned b = (v.x != 0.f ? 1u : 0u) | ((v.y != 0.f ? 1u : 0u) << 8) |
               ((v.z != 0.f ? 1u : 0u) << 16) | ((v.w != 0.f ? 1u : 0u) << 24);
  ((unsigned*)msk)[i] = b;
}

extern "C" void kernel_launch(void* const* d_in, const int* in_sizes, int n_in,
                              void* d_out, int out_size, void* d_ws, size_t ws_size,
                              hipStream_t stream)
{
  const float* x     = (const float*)d_in[0];
  const float* mask  = (const float*)d_in[1];
  const float* w1    = (const float*)d_in[2];
  const float* b1    = (const float*)d_in[3];
  const float* w2    = (const float*)d_in[4];
  const float* b2    = (const float*)d_in[5];
  const float* table = (const float*)d_in[6];
  const int*   pidx  = (const int*)d_in[7];
  float* out = (float*)d_out;
  unsigned char* ws = (unsigned char*)d_ws;
  // ws: w1t 221184 | w2t 73728 | biasm 15925248 | msk 13271040 | qb/kb/vb 35389440 each
  unsigned short* w1t   = (unsigned short*)(ws);
  unsigned short* w2t   = (unsigned short*)(ws + 221184);
  unsigned short* biasm = (unsigned short*)(ws + 294912);
  unsigned char*  msk   = (unsigned char*)(ws + 16220160);
  unsigned short* qb    = (unsigned short*)(ws + 29491200);
  unsigned short* kb    = (unsigned short*)(ws + 64880640);
  unsigned short* vb    = (unsigned short*)(ws + 100270080);

  prep_w   <<<dim3(432),   dim3(256), 0, stream>>>(w1, w2, w1t, w2t);
  prep_bias<<<dim3(324),   dim3(256), 0, stream>>>(table, pidx, biasm);
  prep_mask<<<dim3(12960), dim3(256), 0, stream>>>(mask, msk);
  qkv_kernel<<<dim3(640),  dim3(576), 0, stream>>>(x, b1, w1t, qb, kb, vb);
  attn2_kernel<<<dim3(3840), dim3(256), 0, stream>>>(qb, kb, vb, biasm, msk, w2t, b2, out);
}

// Round 3
// 281.976 us; speedup vs baseline: 1.3924x; 1.3924x over previous
//
#include <hip/hip_runtime.h>

#define NWIN 640
#define ZHW  144
#define DIM  192
#define HEADS 6
#define DH   32
#define TW   64
#define RSCALE 0.17677669529663689f

typedef float f32x4 __attribute__((ext_vector_type(4)));
typedef __bf16 bf16x8 __attribute__((ext_vector_type(8)));

__device__ __forceinline__ unsigned short f2b(float f) {
  unsigned u = __float_as_uint(f);
  u += 0x7fffu + ((u >> 16) & 1u);
  return (unsigned short)(u >> 16);
}
__device__ __forceinline__ float b2f(unsigned v) { return __uint_as_float(v << 16); }

// A/B fragment for mfma_f32_16x16x32_bf16 from a row-major array:
// lane reads elements k0..k0+3 and k0+16..k0+19 of its row (k0 = 4*(lane>>4)).
__device__ __forceinline__ bf16x8 ld_frag(const unsigned short* p) {
  uint2 lo = *(const uint2*)(p);
  uint2 hi = *(const uint2*)(p + 16);
  uint4 u; u.x = lo.x; u.y = lo.y; u.z = hi.x; u.w = hi.y;
  return __builtin_bit_cast(bf16x8, u);
}
#define MFMA16(a, b, c) __builtin_amdgcn_mfma_f32_16x16x32_bf16((a), (b), (c), 0, 0, 0)

// ===================== QKV projection (per window) =========================
// x(144x192 f32, regs as A-frags) @ w1t(576x192 bf16, 6 LDS chunks of 96 n-rows)
// -> qkvb[mat][h][win][144][32] bf16 row-major, coalesced uint4 stores via a
// wave-private LDS bounce tile.
#define WCH 96
#define WB_LD 196
#define BN_LD 40
__global__ __launch_bounds__(576) void qkv_kernel(
    const float* __restrict__ x, const float* __restrict__ b1,
    const unsigned short* __restrict__ w1t, unsigned short* __restrict__ qkvb)
{
  __shared__ __align__(16) unsigned short wb[WCH][WB_LD];   // 37632 B
  __shared__ __align__(16) unsigned short bn[9][16][BN_LD]; // 11520 B
  const int tid = threadIdx.x, wv = tid >> 6, lane = tid & 63;
  const int l15 = lane & 15, g = lane >> 4;
  const int win = blockIdx.x;

  // per-wave x A-fragments: rows 16wv..16wv+15, lane holds row l15
  bf16x8 xa[6];
  {
    const float* xrow = x + ((size_t)win * ZHW + 16 * wv + l15) * DIM;
    #pragma unroll
    for (int kk = 0; kk < 6; ++kk) {
      float4 lo = *(const float4*)(xrow + kk * 32 + 4 * g);
      float4 hi = *(const float4*)(xrow + kk * 32 + 16 + 4 * g);
      uint4 u;
      u.x = (unsigned)f2b(lo.x) | ((unsigned)f2b(lo.y) << 16);
      u.y = (unsigned)f2b(lo.z) | ((unsigned)f2b(lo.w) << 16);
      u.z = (unsigned)f2b(hi.x) | ((unsigned)f2b(hi.y) << 16);
      u.w = (unsigned)f2b(hi.z) | ((unsigned)f2b(hi.w) << 16);
      xa[kk] = __builtin_bit_cast(bf16x8, u);
    }
  }
  #pragma unroll 1
  for (int ch = 0; ch < 6; ++ch) {      // n-cols [96ch, 96ch+96)
    __syncthreads();                    // previous chunk's wb readers done
    {
      const uint2* wsrc = (const uint2*)(w1t + (size_t)ch * WCH * DIM);
      #pragma unroll 1
      for (int i = tid; i < WCH * DIM / 4; i += 576) {
        int e = i * 4, r = e / DIM, c = e - r * DIM;
        *(uint2*)(&wb[r][c]) = wsrc[i];
      }
    }
    __syncthreads();
    const int mat = ch >> 1;
    #pragma unroll 1
    for (int hh = 0; hh < 3; ++hh) {    // head within chunk
      const int h = (ch & 1) * 3 + hh;
      f32x4 acc[2];
      {
        float bv0 = b1[ch * WCH + hh * 32 + l15];
        float bv1 = b1[ch * WCH + hh * 32 + 16 + l15];
        acc[0][0] = bv0; acc[0][1] = bv0; acc[0][2] = bv0; acc[0][3] = bv0;
        acc[1][0] = bv1; acc[1][1] = bv1; acc[1][2] = bv1; acc[1][3] = bv1;
      }
      const unsigned short* br0 = &wb[hh * 32 + l15][4 * g];
      const unsigned short* br1 = &wb[hh * 32 + 16 + l15][4 * g];
      #pragma unroll
      for (int kk = 0; kk < 6; ++kk) {
        acc[0] = MFMA16(xa[kk], ld_frag(br0 + kk * 32), acc[0]);
        acc[1] = MFMA16(xa[kk], ld_frag(br1 + kk * 32), acc[1]);
      }
      // bounce: acc (rows 4g+j, col nt2*16+l15) -> coalesced row-major store
      #pragma unroll
      for (int nt2 = 0; nt2 < 2; ++nt2)
        #pragma unroll
        for (int j = 0; j < 4; ++j)
          bn[wv][4 * g + j][nt2 * 16 + l15] = f2b(acc[nt2][j]);
      __builtin_amdgcn_s_waitcnt(0xC07F);  // lgkmcnt(0): wave's LDS writes done
      uint4 val = *(uint4*)(&bn[wv][lane >> 2][(lane & 3) * 8]);
      const size_t gbase = ((size_t)(mat * HEADS + h) * NWIN + win) * (ZHW * DH);
      *(uint4*)(qkvb + gbase + (size_t)(16 * wv + (lane >> 2)) * DH + (lane & 3) * 8) = val;
      __builtin_amdgcn_s_waitcnt(0xC07F);  // read done before next hh overwrites bn
    }
  }
}

// ===================== attention per (win, head) ===========================
#define KS_LD 36
#define VT_LD 164
__global__ __launch_bounds__(256) void attn3_kernel(
    const unsigned short* __restrict__ qkvb, const unsigned short* __restrict__ biasz,
    const unsigned* __restrict__ mz, unsigned short* __restrict__ xbuf)
{
  __shared__ __align__(16) unsigned short qs[ZHW][KS_LD];  // 10368 B
  __shared__ __align__(16) unsigned short ks[ZHW][KS_LD];  // 10368 B
  __shared__ __align__(16) unsigned short vt[DH][VT_LD];   // 10496 B
  const int tid = threadIdx.x, wv = tid >> 6, lane = tid & 63;
  const int l15 = lane & 15, g = lane >> 4;
  const int m = blockIdx.x, h = m / NWIN, win = m - h * NWIN, wtype = win & (TW - 1);

  const unsigned short* qg = qkvb + ((size_t)h * NWIN + win) * (ZHW * DH);
  const unsigned short* kg = qg + (size_t)HEADS * NWIN * (ZHW * DH);
  const unsigned short* vg = kg + (size_t)HEADS * NWIN * (ZHW * DH);
  {
    const uint2* qsrc = (const uint2*)qg;
    const uint2* ksrc = (const uint2*)kg;
    #pragma unroll 1
    for (int i = tid; i < ZHW * DH / 4; i += 256) {
      int e = i * 4, r = e >> 5, c = e & 31;
      *(uint2*)(&qs[r][c]) = qsrc[i];
      *(uint2*)(&ks[r][c]) = ksrc[i];
    }
    const uint2* vsrc = (const uint2*)vg;
    #pragma unroll 1
    for (int i = tid; i < ZHW * DH / 4; i += 256) {
      int e = i * 4, r = e >> 5, c = e & 31;   // token r, dims c..c+3
      uint2 v = vsrc[i];
      vt[c + 0][r] = (unsigned short)(v.x);
      vt[c + 1][r] = (unsigned short)(v.x >> 16);
      vt[c + 2][r] = (unsigned short)(v.y);
      vt[c + 3][r] = (unsigned short)(v.y >> 16);
    }
    #pragma unroll 1
    for (int i = tid; i < DH * (VT_LD - ZHW); i += 256) {
      int r = i / (VT_LD - ZHW), c = ZHW + i - r * (VT_LD - ZHW);
      vt[r][c] = 0;
    }
  }
  __syncthreads();

  const uint2* bz = (const uint2*)biasz + (size_t)(wtype * HEADS + h) * 81 * 64;
  const unsigned* mzp = mz + (size_t)win * 81 * 64;

  #pragma unroll 1
  for (int s = wv; s < 9; s += 4) {
    const int q = 16 * s + l15;
    bf16x8 bq = ld_frag(&qs[q][4 * g]);
    f32x4 st[9];
    #pragma unroll
    for (int kst = 0; kst < 9; ++kst) {
      bf16x8 ak = ld_frag(&ks[16 * kst + l15][4 * g]);
      f32x4 z; z[0] = 0.f; z[1] = 0.f; z[2] = 0.f; z[3] = 0.f;
      st[kst] = MFMA16(ak, bq, z);   // St[kk=16kst+4g+j][q]
    }
    float mx = -1e30f;
    #pragma unroll
    for (int kst = 0; kst < 9; ++kst) {
      uint2 bb = bz[(s * 9 + kst) * 64 + lane];
      unsigned mm = mzp[(s * 9 + kst) * 64 + lane];
      f32x4 sv = st[kst];
      sv[0] = sv[0] * RSCALE + b2f(bb.x & 0xffffu) + ((mm & 0xffu)       ? -100.f : 0.f);
      sv[1] = sv[1] * RSCALE + b2f(bb.x >> 16)     + ((mm & 0xff00u)     ? -100.f : 0.f);
      sv[2] = sv[2] * RSCALE + b2f(bb.y & 0xffffu) + ((mm & 0xff0000u)   ? -100.f : 0.f);
      sv[3] = sv[3] * RSCALE + b2f(bb.y >> 16)     + ((mm & 0xff000000u) ? -100.f : 0.f);
      st[kst] = sv;
      mx = fmaxf(mx, fmaxf(fmaxf(sv[0], sv[1]), fmaxf(sv[2], sv[3])));
    }
    mx = fmaxf(mx, __shfl_xor(mx, 16));
    mx = fmaxf(mx, __shfl_xor(mx, 32));
    float sum = 0.f;
    #pragma unroll
    for (int kst = 0; kst < 9; ++kst) {
      f32x4 sv = st[kst];
      sv[0] = __expf(sv[0] - mx); sv[1] = __expf(sv[1] - mx);
      sv[2] = __expf(sv[2] - mx); sv[3] = __expf(sv[3] - mx);
      st[kst] = sv;
      sum += sv[0] + sv[1] + sv[2] + sv[3];
    }
    sum += __shfl_xor(sum, 16);
    sum += __shfl_xor(sum, 32);
    const float inv = 1.f / sum;
    bf16x8 pb[5];
    #pragma unroll
    for (int s5 = 0; s5 < 5; ++s5) {
      unsigned short e[8];
      #pragma unroll
      for (int j = 0; j < 4; ++j) e[j] = f2b(st[2 * s5][j] * inv);
      if (s5 < 4) {
        #pragma unroll
        for (int j = 0; j < 4; ++j) e[4 + j] = f2b(st[2 * s5 + 1][j] * inv);
      } else {
        e[4] = 0; e[5] = 0; e[6] = 0; e[7] = 0;
      }
      uint4 u;
      u.x = (unsigned)e[0] | ((unsigned)e[1] << 16);
      u.y = (unsigned)e[2] | ((unsigned)e[3] << 16);
      u.z = (unsigned)e[4] | ((unsigned)e[5] << 16);
      u.w = (unsigned)e[6] | ((unsigned)e[7] << 16);
      pb[s5] = __builtin_bit_cast(bf16x8, u);
    }
    // O^T store into swapaxes-scrambled xbuf: row 24m + q/6, col (q%6)*32 + d
    const int r = q / 6, cb = (q - r * 6) * DH;
    unsigned short* xrow = xbuf + (size_t)(24 * m + r) * DIM + cb + 4 * g;
    #pragma unroll
    for (int dt = 0; dt < 2; ++dt) {
      const unsigned short* vrow = &vt[dt * 16 + l15][4 * g];
      f32x4 ot; ot[0] = 0.f; ot[1] = 0.f; ot[2] = 0.f; ot[3] = 0.f;
      #pragma unroll
      for (int s5 = 0; s5 < 5; ++s5)
        ot = MFMA16(ld_frag(vrow + s5 * 32), pb[s5], ot);
      uint2 pk;
      pk.x = (unsigned)f2b(ot[0]) | ((unsigned)f2b(ot[1]) << 16);
      pk.y = (unsigned)f2b(ot[2]) | ((unsigned)f2b(ot[3]) << 16);
      *(uint2*)(xrow + dt * 16) = pk;
    }
  }
}

// ============ out projection: xbuf(92160x192 bf16) @ w2 + b2 ==============
__global__ __launch_bounds__(512) void proj_kernel(
    const unsigned short* __restrict__ xbuf, const unsigned short* __restrict__ w2t,
    const float* __restrict__ b2, float* __restrict__ out)
{
  __shared__ __align__(16) unsigned short wb[WCH][WB_LD];  // 37632 B
  const int tid = threadIdx.x, wv = tid >> 6, lane = tid & 63;
  const int l15 = lane & 15, g = lane >> 4;
  const int r0 = blockIdx.x * 128;
  bf16x8 xa[6];
  {
    const unsigned short* xrow = xbuf + (size_t)(r0 + 16 * wv + l15) * DIM;
    #pragma unroll
    for (int kk = 0; kk < 6; ++kk) xa[kk] = ld_frag(xrow + kk * 32 + 4 * g);
  }
  #pragma unroll 1
  for (int ch = 0; ch < 2; ++ch) {
    __syncthreads();
    {
      const uint2* wsrc = (const uint2*)(w2t + (size_t)ch * WCH * DIM);
      #pragma unroll 1
      for (int i = tid; i < WCH * DIM / 4; i += 512) {
        int e = i * 4, r = e / DIM, c = e - r * DIM;
        *(uint2*)(&wb[r][c]) = wsrc[i];
      }
    }
    __syncthreads();
    #pragma unroll 1
    for (int nt = 0; nt < 6; ++nt) {
      const int n = ch * WCH + nt * 16 + l15;
      float bv = b2[n];
      f32x4 acc; acc[0] = bv; acc[1] = bv; acc[2] = bv; acc[3] = bv;
      const unsigned short* brow = &wb[nt * 16 + l15][4 * g];
      #pragma unroll
      for (int kk = 0; kk < 6; ++kk) acc = MFMA16(xa[kk], ld_frag(brow + kk * 32), acc);
      #pragma unroll
      for (int j = 0; j < 4; ++j)
        out[(size_t)(r0 + 16 * wv + 4 * g + j) * DIM + n] = acc[j];
    }
  }
}

// ---- prep: transpose weights to bf16 n-major ----
__global__ void prep_w(const float* __restrict__ w1, const float* __restrict__ w2,
                       unsigned short* __restrict__ w1t, unsigned short* __restrict__ w2t)
{
  int i = blockIdx.x * 256 + threadIdx.x;
  if (i < 576 * 192) { int n = i / 192, k = i % 192; w1t[i] = f2b(w1[k * 576 + n]); }
  if (i < 192 * 192) { int n = i / 192, k = i % 192; w2t[i] = f2b(w2[k * 192 + n]); }
}

// ---- prep: biasm[wh][q][kk] bf16 via LDS transpose ----
__global__ void prep_bias(const float* __restrict__ table, const int* __restrict__ pidx,
                          unsigned short* __restrict__ biasm)
{
  __shared__ float ld[64 * 385];
  const int tid = threadIdx.x;
  const int p0 = blockIdx.x * 64;
  #pragma unroll 1
  for (int i = tid; i < 64 * 384; i += 256) {
    int pl = i / 384, wh = i % 384;
    ld[pl * 385 + wh] = table[(size_t)pidx[p0 + pl] * 384 + wh];
  }
  __syncthreads();
  #pragma unroll 1
  for (int i = tid; i < 384 * 64; i += 256) {
    int wh = i / 64, pl = i % 64;
    biasm[(size_t)wh * (ZHW * ZHW) + p0 + pl] = f2b(ld[pl * 385 + wh]);
  }
}

// ---- prep: swizzle biasm -> biasz[((wh*9+s)*9+kst)*64+lane] (uint2 frags) ----
__global__ void bias_swz(const unsigned short* __restrict__ biasm,
                         unsigned short* __restrict__ biasz)
{
  int gid = blockIdx.x * 256 + threadIdx.x;
  int lane = gid & 63, t = gid >> 6;
  int kst = t % 9; t /= 9;
  int s = t % 9, wh = t / 9;
  int l15 = lane & 15, g = lane >> 4;
  const uint2* src = (const uint2*)(biasm + (size_t)wh * (ZHW * ZHW) +
                                    (16 * s + l15) * ZHW + 16 * kst + 4 * g);
  ((uint2*)biasz)[gid] = *src;
}

// ---- prep: mask f32 -> mz[((win*9+s)*9+kst)*64+lane] (u32 = 4 flag bytes) ----
__global__ void prep_mask(const float* __restrict__ mask, unsigned* __restrict__ mz)
{
  int gid = blockIdx.x * 256 + threadIdx.x;
  int lane = gid & 63, t = gid >> 6;
  int kst = t % 9; t /= 9;
  int s = t % 9, win = t / 9;
  int l15 = lane & 15, g = lane >> 4;
  float4 v = *(const float4*)(mask + (size_t)win * (ZHW * ZHW) +
                              (16 * s + l15) * ZHW + 16 * kst + 4 * g);
  mz[gid] = (v.x != 0.f ? 1u : 0u) | ((v.y != 0.f ? 1u : 0u) << 8) |
            ((v.z != 0.f ? 1u : 0u) << 16) | ((v.w != 0.f ? 1u : 0u) << 24);
}

extern "C" void kernel_launch(void* const* d_in, const int* in_sizes, int n_in,
                              void* d_out, int out_size, void* d_ws, size_t ws_size,
                              hipStream_t stream)
{
  const float* x     = (const float*)d_in[0];
  const float* mask  = (const float*)d_in[1];
  const float* w1    = (const float*)d_in[2];
  const float* b1    = (const float*)d_in[3];
  const float* w2    = (const float*)d_in[4];
  const float* b2    = (const float*)d_in[5];
  const float* table = (const float*)d_in[6];
  const int*   pidx  = (const int*)d_in[7];
  float* out = (float*)d_out;
  unsigned char* ws = (unsigned char*)d_ws;
  // ws: w1t 221184 | w2t 73728 | biasz 15925248 | mz 13271040 |
  //     qkvb 106168320 (biasm aliases its head, dead before qkv runs) |
  //     xbuf 35389440   -> total 171,048,960 B
  unsigned short* w1t   = (unsigned short*)(ws);
  unsigned short* w2t   = (unsigned short*)(ws + 221184);
  unsigned short* biasz = (unsigned short*)(ws + 294912);
  unsigned*       mz    = (unsigned*)(ws + 16220160);
  unsigned short* qkvb  = (unsigned short*)(ws + 29491200);
  unsigned short* biasm = qkvb;  // alias: used only before qkv_kernel
  unsigned short* xbuf  = (unsigned short*)(ws + 135659520);

  prep_w   <<<dim3(432),   dim3(256), 0, stream>>>(w1, w2, w1t, w2t);
  prep_bias<<<dim3(324),   dim3(256), 0, stream>>>(table, pidx, biasm);
  bias_swz <<<dim3(7776),  dim3(256), 0, stream>>>(biasm, biasz);
  prep_mask<<<dim3(12960), dim3(256), 0, stream>>>(mask, mz);
  qkv_kernel<<<dim3(640),  dim3(576), 0, stream>>>(x, b1, w1t, qkvb);
  attn3_kernel<<<dim3(3840), dim3(256), 0, stream>>>(qkvb, biasz, mz, xbuf);
  proj_kernel<<<dim3(720), dim3(512), 0, stream>>>(xbuf, w2t, b2, out);
}

// Round 4
// 265.214 us; speedup vs baseline: 1.4805x; 1.0632x over previous
//
#include <hip/hip_runtime.h>

#define NWIN 640
#define ZHW  144
#define DIM  192
#define HEADS 6
#define DH   32
#define TW   64
#define RSCALE 0.17677669529663689f

typedef float f32x4 __attribute__((ext_vector_type(4)));
typedef __bf16 bf16x8 __attribute__((ext_vector_type(8)));

__device__ __forceinline__ unsigned short f2b(float f) {
  unsigned u = __float_as_uint(f);
  u += 0x7fffu + ((u >> 16) & 1u);
  return (unsigned short)(u >> 16);
}
__device__ __forceinline__ float b2f(unsigned v) { return __uint_as_float(v << 16); }

// A/B fragment for mfma_f32_16x16x32_bf16 from a row-major array:
// lane reads elements k0..k0+3 and k0+16..k0+19 of its row (k0 = 4*(lane>>4)).
__device__ __forceinline__ bf16x8 ld_frag(const unsigned short* p) {
  uint2 lo = *(const uint2*)(p);
  uint2 hi = *(const uint2*)(p + 16);
  uint4 u; u.x = lo.x; u.y = lo.y; u.z = hi.x; u.w = hi.y;
  return __builtin_bit_cast(bf16x8, u);
}
#define MFMA16(a, b, c) __builtin_amdgcn_mfma_f32_16x16x32_bf16((a), (b), (c), 0, 0, 0)

// ============ conv_x: x f32 -> xb2 bf16 in A-fragment-packed order ==========
// xb2 uint4 index ((row/16)*6 + kk)*64 + lane holds x[16rt + (lane&15)]
// [32kk + 4*(lane>>4) + {0..3}] and [... + 16 + {0..3}].
__global__ __launch_bounds__(256) void conv_x(const float* __restrict__ x,
                                              unsigned short* __restrict__ xb2)
{
  __shared__ __align__(16) unsigned short xl[128][196];
  const int tid = threadIdx.x;
  const int r0 = blockIdx.x * 128;
  const float4* src = (const float4*)(x + (size_t)r0 * DIM);
  #pragma unroll 1
  for (int i = tid; i < 128 * DIM / 4; i += 256) {
    float4 v = src[i];
    int e = i * 4, r = e / DIM, c = e - r * DIM;
    uint2 pk;
    pk.x = (unsigned)f2b(v.x) | ((unsigned)f2b(v.y) << 16);
    pk.y = (unsigned)f2b(v.z) | ((unsigned)f2b(v.w) << 16);
    *(uint2*)(&xl[r][c]) = pk;
  }
  __syncthreads();
  uint4* dst = (uint4*)xb2 + (size_t)blockIdx.x * 3072;
  #pragma unroll 1
  for (int o = tid; o < 8 * 6 * 64; o += 256) {
    int rt = o / 384, rem = o - rt * 384, kk = rem >> 6, ln = rem & 63;
    const unsigned short* p = &xl[16 * rt + (ln & 15)][32 * kk + 4 * (ln >> 4)];
    uint2 lo = *(const uint2*)p;
    uint2 hi = *(const uint2*)(p + 16);
    uint4 u; u.x = lo.x; u.y = lo.y; u.z = hi.x; u.w = hi.y;
    dst[o] = u;
  }
}

// ===================== QKV projection (tiled GEMM) =========================
// xb2(92160x192, A-frag-packed) @ w1t(576x192) + b1 -> qkvb fragment-packed:
// per (mat,h,win) tile of 144x32, uint2 index (rg*2+ct)*64+lane holds
// rows 16rg+4*(lane>>4)+{0..3}, col d = 16ct+(lane&15).
#define WCH 96
#define QWB_LD 196
__global__ __launch_bounds__(256) void qkv_kernel(
    const unsigned short* __restrict__ xb2, const float* __restrict__ b1,
    const unsigned short* __restrict__ w1t, unsigned short* __restrict__ qkvb)
{
  __shared__ __align__(16) unsigned short wb[WCH][QWB_LD];
  const int tid = threadIdx.x, wv = tid >> 6, lane = tid & 63;
  const int l15 = lane & 15, g = lane >> 4;
  const int mt = blockIdx.x / 6, ch = blockIdx.x - mt * 6;
  const int r0 = mt * 128;

  {
    const uint4* wsrc = (const uint4*)(w1t + (size_t)ch * WCH * DIM);
    #pragma unroll 1
    for (int i = tid; i < WCH * DIM / 8; i += 256) {
      int e = i * 8, r = e / DIM, c = e - r * DIM;
      *(uint4*)(&wb[r][c]) = wsrc[i];
    }
  }
  bf16x8 xa[2][6];
  {
    const uint4* asrc = (const uint4*)xb2;
    const int rt0 = mt * 8 + 2 * wv;
    #pragma unroll
    for (int rt = 0; rt < 2; ++rt)
      #pragma unroll
      for (int kk = 0; kk < 6; ++kk)
        xa[rt][kk] = __builtin_bit_cast(bf16x8,
            asrc[((size_t)(rt0 + rt) * 6 + kk) * 64 + lane]);
  }
  __syncthreads();
  const int mat = ch >> 1;
  #pragma unroll 1
  for (int hh = 0; hh < 3; ++hh) {
    const int h = (ch & 1) * 3 + hh;
    f32x4 acc[2][2];
    {
      float bv0 = b1[ch * WCH + hh * 32 + l15];
      float bv1 = b1[ch * WCH + hh * 32 + 16 + l15];
      #pragma unroll
      for (int rt = 0; rt < 2; ++rt) {
        acc[rt][0][0] = bv0; acc[rt][0][1] = bv0; acc[rt][0][2] = bv0; acc[rt][0][3] = bv0;
        acc[rt][1][0] = bv1; acc[rt][1][1] = bv1; acc[rt][1][2] = bv1; acc[rt][1][3] = bv1;
      }
    }
    const unsigned short* br0 = &wb[hh * 32 + l15][4 * g];
    const unsigned short* br1 = &wb[hh * 32 + 16 + l15][4 * g];
    #pragma unroll
    for (int kk = 0; kk < 6; ++kk) {
      bf16x8 b0 = ld_frag(br0 + kk * 32);
      bf16x8 b1f = ld_frag(br1 + kk * 32);
      acc[0][0] = MFMA16(xa[0][kk], b0, acc[0][0]);
      acc[0][1] = MFMA16(xa[0][kk], b1f, acc[0][1]);
      acc[1][0] = MFMA16(xa[1][kk], b0, acc[1][0]);
      acc[1][1] = MFMA16(xa[1][kk], b1f, acc[1][1]);
    }
    // fragment-packed coalesced stores: one uint2 per (rt, ct) per lane
    #pragma unroll
    for (int rt = 0; rt < 2; ++rt) {
      const int row16 = r0 + 32 * wv + 16 * rt;
      const int win = row16 / 144, rg = (row16 - win * 144) >> 4;
      uint2* dst = (uint2*)qkvb + ((size_t)(mat * HEADS + h) * NWIN + win) * 1152
                   + (rg * 2) * 64 + lane;
      #pragma unroll
      for (int ct = 0; ct < 2; ++ct) {
        uint2 pk;
        pk.x = (unsigned)f2b(acc[rt][ct][0]) | ((unsigned)f2b(acc[rt][ct][1]) << 16);
        pk.y = (unsigned)f2b(acc[rt][ct][2]) | ((unsigned)f2b(acc[rt][ct][3]) << 16);
        dst[ct * 64] = pk;
      }
    }
  }
}

// ===================== attention per (win, head) ===========================
#define KS_LD 36
#define VT_LD 164
__global__ __launch_bounds__(256) void attn3_kernel(
    const unsigned short* __restrict__ qkvb, const unsigned short* __restrict__ biasz,
    const unsigned char* __restrict__ msk8, unsigned short* __restrict__ xbuf)
{
  __shared__ __align__(16) unsigned short qs[ZHW][KS_LD];  // 10368 B
  __shared__ __align__(16) unsigned short ks[ZHW][KS_LD];  // 10368 B
  __shared__ __align__(16) unsigned short vt[DH][VT_LD];   // 10496 B
  const int tid = threadIdx.x, wv = tid >> 6, lane = tid & 63;
  const int l15 = lane & 15, g = lane >> 4;
  const int m = blockIdx.x, h = m / NWIN, win = m - h * NWIN, wtype = win & (TW - 1);

  // stage fragment-packed q/k/v
  {
    const uint2* qsrc = (const uint2*)qkvb + ((size_t)h * NWIN + win) * 1152;
    const uint2* ksrc = qsrc + (size_t)HEADS * NWIN * 1152;
    const uint2* vsrc = ksrc + (size_t)HEADS * NWIN * 1152;
    #pragma unroll 1
    for (int i = tid; i < 1152; i += 256) {
      int fid = i >> 6, ln = i & 63;
      int rg = fid >> 1, ct = fid & 1;
      int tok = 16 * rg + 4 * (ln >> 4);
      int d = 16 * ct + (ln & 15);
      uint2 uq = qsrc[i];
      qs[tok + 0][d] = (unsigned short)uq.x;
      qs[tok + 1][d] = (unsigned short)(uq.x >> 16);
      qs[tok + 2][d] = (unsigned short)uq.y;
      qs[tok + 3][d] = (unsigned short)(uq.y >> 16);
      uint2 uk = ksrc[i];
      ks[tok + 0][d] = (unsigned short)uk.x;
      ks[tok + 1][d] = (unsigned short)(uk.x >> 16);
      ks[tok + 2][d] = (unsigned short)uk.y;
      ks[tok + 3][d] = (unsigned short)(uk.y >> 16);
      *(uint2*)(&vt[d][tok]) = vsrc[i];   // v: 4 consecutive tokens
    }
    #pragma unroll 1
    for (int i = tid; i < DH * (VT_LD - ZHW); i += 256) {
      int r = i / (VT_LD - ZHW), c = ZHW + i - r * (VT_LD - ZHW);
      vt[r][c] = 0;
    }
  }
  __syncthreads();

  const uint2* bz = (const uint2*)biasz + (size_t)(wtype * HEADS + h) * 81 * 64;
  const unsigned char* mb = msk8 + (size_t)win * 2592;

  #pragma unroll 1
  for (int s = wv; s < 9; s += 4) {
    const int q = 16 * s + l15;
    bf16x8 bq = ld_frag(&qs[q][4 * g]);
    f32x4 st[9];
    #pragma unroll
    for (int kst = 0; kst < 9; ++kst) {
      bf16x8 ak = ld_frag(&ks[16 * kst + l15][4 * g]);
      f32x4 z; z[0] = 0.f; z[1] = 0.f; z[2] = 0.f; z[3] = 0.f;
      st[kst] = MFMA16(ak, bq, z);   // St[kk=16kst+4g+j][q]
    }
    const unsigned char* mrow = mb + q * 18 + (g >> 1);
    const int nsh = (g & 1) * 4;
    float mx = -1e30f;
    #pragma unroll
    for (int kst = 0; kst < 9; ++kst) {
      uint2 bb = bz[(s * 9 + kst) * 64 + lane];
      unsigned mm = (unsigned)(mrow[2 * kst]) >> nsh;
      f32x4 sv = st[kst];
      sv[0] = sv[0] * RSCALE + b2f(bb.x & 0xffffu) + ((mm & 1u) ? -100.f : 0.f);
      sv[1] = sv[1] * RSCALE + b2f(bb.x >> 16)     + ((mm & 2u) ? -100.f : 0.f);
      sv[2] = sv[2] * RSCALE + b2f(bb.y & 0xffffu) + ((mm & 4u) ? -100.f : 0.f);
      sv[3] = sv[3] * RSCALE + b2f(bb.y >> 16)     + ((mm & 8u) ? -100.f : 0.f);
      st[kst] = sv;
      mx = fmaxf(mx, fmaxf(fmaxf(sv[0], sv[1]), fmaxf(sv[2], sv[3])));
    }
    mx = fmaxf(mx, __shfl_xor(mx, 16));
    mx = fmaxf(mx, __shfl_xor(mx, 32));
    float sum = 0.f;
    #pragma unroll
    for (int kst = 0; kst < 9; ++kst) {
      f32x4 sv = st[kst];
      sv[0] = __expf(sv[0] - mx); sv[1] = __expf(sv[1] - mx);
      sv[2] = __expf(sv[2] - mx); sv[3] = __expf(sv[3] - mx);
      st[kst] = sv;
      sum += sv[0] + sv[1] + sv[2] + sv[3];
    }
    sum += __shfl_xor(sum, 16);
    sum += __shfl_xor(sum, 32);
    const float inv = 1.f / sum;
    bf16x8 pb[5];
    #pragma unroll
    for (int s5 = 0; s5 < 5; ++s5) {
      unsigned short e[8];
      #pragma unroll
      for (int j = 0; j < 4; ++j) e[j] = f2b(st[2 * s5][j] * inv);
      if (s5 < 4) {
        #pragma unroll
        for (int j = 0; j < 4; ++j) e[4 + j] = f2b(st[2 * s5 + 1][j] * inv);
      } else {
        e[4] = 0; e[5] = 0; e[6] = 0; e[7] = 0;
      }
      uint4 u;
      u.x = (unsigned)e[0] | ((unsigned)e[1] << 16);
      u.y = (unsigned)e[2] | ((unsigned)e[3] << 16);
      u.z = (unsigned)e[4] | ((unsigned)e[5] << 16);
      u.w = (unsigned)e[6] | ((unsigned)e[7] << 16);
      pb[s5] = __builtin_bit_cast(bf16x8, u);
    }
    // O^T store into swapaxes-scrambled xbuf: row 24m + q/6, col (q%6)*32 + d
    const int r = q / 6, cb = (q - r * 6) * DH;
    unsigned short* xrow = xbuf + (size_t)(24 * m + r) * DIM + cb + 4 * g;
    #pragma unroll
    for (int dt = 0; dt < 2; ++dt) {
      const unsigned short* vrow = &vt[dt * 16 + l15][4 * g];
      f32x4 ot; ot[0] = 0.f; ot[1] = 0.f; ot[2] = 0.f; ot[3] = 0.f;
      #pragma unroll
      for (int s5 = 0; s5 < 5; ++s5)
        ot = MFMA16(ld_frag(vrow + s5 * 32), pb[s5], ot);
      uint2 pk;
      pk.x = (unsigned)f2b(ot[0]) | ((unsigned)f2b(ot[1]) << 16);
      pk.y = (unsigned)f2b(ot[2]) | ((unsigned)f2b(ot[3]) << 16);
      *(uint2*)(xrow + dt * 16) = pk;
    }
  }
}

// ============ out projection: xbuf(92160x192 bf16) @ w2 + b2 ==============
__global__ __launch_bounds__(512) void proj_kernel(
    const unsigned short* __restrict__ xbuf, const unsigned short* __restrict__ w2t,
    const float* __restrict__ b2, float* __restrict__ out)
{
  __shared__ __align__(16) unsigned short wb[WCH][QWB_LD];  // 37632 B
  const int tid = threadIdx.x, wv = tid >> 6, lane = tid & 63;
  const int l15 = lane & 15, g = lane >> 4;
  const int r0 = blockIdx.x * 128;
  bf16x8 xa[6];
  {
    const unsigned short* xrow = xbuf + (size_t)(r0 + 16 * wv + l15) * DIM;
    #pragma unroll
    for (int kk = 0; kk < 6; ++kk) xa[kk] = ld_frag(xrow + kk * 32 + 4 * g);
  }
  #pragma unroll 1
  for (int ch = 0; ch < 2; ++ch) {
    __syncthreads();
    {
      const uint2* wsrc = (const uint2*)(w2t + (size_t)ch * WCH * DIM);
      #pragma unroll 1
      for (int i = tid; i < WCH * DIM / 4; i += 512) {
        int e = i * 4, r = e / DIM, c = e - r * DIM;
        *(uint2*)(&wb[r][c]) = wsrc[i];
      }
    }
    __syncthreads();
    #pragma unroll 1
    for (int nt = 0; nt < 6; ++nt) {
      const int n = ch * WCH + nt * 16 + l15;
      float bv = b2[n];
      f32x4 acc; acc[0] = bv; acc[1] = bv; acc[2] = bv; acc[3] = bv;
      const unsigned short* brow = &wb[nt * 16 + l15][4 * g];
      #pragma unroll
      for (int kk = 0; kk < 6; ++kk) acc = MFMA16(xa[kk], ld_frag(brow + kk * 32), acc);
      #pragma unroll
      for (int j = 0; j < 4; ++j)
        out[(size_t)(r0 + 16 * wv + 4 * g + j) * DIM + n] = acc[j];
    }
  }
}

// ---- prep: transpose weights to bf16 n-major ----
__global__ void prep_w(const float* __restrict__ w1, const float* __restrict__ w2,
                       unsigned short* __restrict__ w1t, unsigned short* __restrict__ w2t)
{
  int i = blockIdx.x * 256 + threadIdx.x;
  if (i < 576 * 192) { int n = i / 192, k = i % 192; w1t[i] = f2b(w1[k * 576 + n]); }
  if (i < 192 * 192) { int n = i / 192, k = i % 192; w2t[i] = f2b(w2[k * 192 + n]); }
}

// ---- prep: biasm[wh][q][kk] bf16 via LDS transpose ----
__global__ void prep_bias(const float* __restrict__ table, const int* __restrict__ pidx,
                          unsigned short* __restrict__ biasm)
{
  __shared__ float ld[64 * 385];
  const int tid = threadIdx.x;
  const int p0 = blockIdx.x * 64;
  #pragma unroll 1
  for (int i = tid; i < 64 * 384; i += 256) {
    int pl = i / 384, wh = i % 384;
    ld[pl * 385 + wh] = table[(size_t)pidx[p0 + pl] * 384 + wh];
  }
  __syncthreads();
  #pragma unroll 1
  for (int i = tid; i < 384 * 64; i += 256) {
    int wh = i / 64, pl = i % 64;
    biasm[(size_t)wh * (ZHW * ZHW) + p0 + pl] = f2b(ld[pl * 385 + wh]);
  }
}

// ---- prep: swizzle biasm -> biasz[((wh*9+s)*9+kst)*64+lane] (uint2 frags) ----
__global__ void bias_swz(const unsigned short* __restrict__ biasm,
                         unsigned short* __restrict__ biasz)
{
  int gid = blockIdx.x * 256 + threadIdx.x;
  int lane = gid & 63, t = gid >> 6;
  int kst = t % 9; t /= 9;
  int s = t % 9, wh = t / 9;
  int l15 = lane & 15, g = lane >> 4;
  const uint2* src = (const uint2*)(biasm + (size_t)wh * (ZHW * ZHW) +
                                    (16 * s + l15) * ZHW + 16 * kst + 4 * g);
  ((uint2*)biasz)[gid] = *src;
}

// ---- prep: mask f32 -> bitpacked (1 bit per element, byte = 8 elems) ----
__global__ void prep_mask(const float* __restrict__ mask, unsigned char* __restrict__ msk8)
{
  int gid = blockIdx.x * 256 + threadIdx.x;  // one byte = 8 consecutive elems
  const float4* src = (const float4*)(mask + (size_t)gid * 8);
  float4 a = src[0], b = src[1];
  unsigned v = (a.x != 0.f ? 1u : 0u) | (a.y != 0.f ? 2u : 0u) |
               (a.z != 0.f ? 4u : 0u) | (a.w != 0.f ? 8u : 0u) |
               (b.x != 0.f ? 16u : 0u) | (b.y != 0.f ? 32u : 0u) |
               (b.z != 0.f ? 64u : 0u) | (b.w != 0.f ? 128u : 0u);
  msk8[gid] = (unsigned char)v;
}

extern "C" void kernel_launch(void* const* d_in, const int* in_sizes, int n_in,
                              void* d_out, int out_size, void* d_ws, size_t ws_size,
                              hipStream_t stream)
{
  const float* x     = (const float*)d_in[0];
  const float* mask  = (const float*)d_in[1];
  const float* w1    = (const float*)d_in[2];
  const float* b1    = (const float*)d_in[3];
  const float* w2    = (const float*)d_in[4];
  const float* b2    = (const float*)d_in[5];
  const float* table = (const float*)d_in[6];
  const int*   pidx  = (const int*)d_in[7];
  float* out = (float*)d_out;
  unsigned char* ws = (unsigned char*)d_ws;
  // ws: w1t 221184 | w2t 73728 | biasz 15925248 | msk8 1658880 |
  //     qkvb 106168320 (biasm aliases head; dead before qkv) |
  //     xbuf 35389440 (xb2 aliases; dead before attn3) -> 171,048,960 B
  unsigned short* w1t   = (unsigned short*)(ws);
  unsigned short* w2t   = (unsigned short*)(ws + 221184);
  unsigned short* biasz = (unsigned short*)(ws + 294912);
  unsigned char*  msk8  = (unsigned char*)(ws + 16220160);
  unsigned short* qkvb  = (unsigned short*)(ws + 29491200);
  unsigned short* biasm = qkvb;   // alias: consumed by bias_swz before qkv runs
  unsigned short* xbuf  = (unsigned short*)(ws + 135659520);
  unsigned short* xb2   = xbuf;   // alias: consumed by qkv before attn3 writes

  prep_w   <<<dim3(432),  dim3(256), 0, stream>>>(w1, w2, w1t, w2t);
  prep_bias<<<dim3(324),  dim3(256), 0, stream>>>(table, pidx, biasm);
  bias_swz <<<dim3(7776), dim3(256), 0, stream>>>(biasm, biasz);
  prep_mask<<<dim3(6480), dim3(256), 0, stream>>>(mask, msk8);
  conv_x   <<<dim3(720),  dim3(256), 0, stream>>>(x, xb2);
  qkv_kernel<<<dim3(4320), dim3(256), 0, stream>>>(xb2, b1, w1t, qkvb);
  attn3_kernel<<<dim3(3840), dim3(256), 0, stream>>>(qkvb, biasz, msk8, xbuf);
  proj_kernel<<<dim3(720), dim3(512), 0, stream>>>(xbuf, w2t, b2, out);
}